// Round 3
// baseline (480.619 us; speedup 1.0000x reference)
//
#include <hip/hip_runtime.h>

#define MBLK 32

typedef __attribute__((ext_vector_type(8))) short bf16x8;
typedef __attribute__((ext_vector_type(4))) float f32x4;

__device__ __forceinline__ unsigned short f2bf(float x){
  unsigned int u = __float_as_uint(x);
  u = u + 0x7FFFu + ((u >> 16) & 1u);
  return (unsigned short)(u >> 16);
}
__device__ __forceinline__ float bf2f(unsigned short s){
  return __uint_as_float(((unsigned int)s) << 16);
}
__device__ __forceinline__ float sigm(float x){
  return __builtin_amdgcn_rcpf(1.0f + __expf(-x));
}
__device__ __forceinline__ float tanh_(float x){
  return 1.0f - 2.0f*__builtin_amdgcn_rcpf(__expf(2.0f*x) + 1.0f);
}

// 1024 threads = 16 waves: waves 0-7 own samples 0-15 (mtb=0), waves 8-15 own
// samples 16-31 (mtb=16). Within each half, wave w8 owns hidden units
// jw = w8*16 + (lane&15) for all 4 gates. Gate weights for nt=0..2 live in
// registers (72 VGPR); nt=3 ('o' gate) lives in LDS as pre-packed MFMA
// fragments (49 KB) so total regs fit the 128/lane cap that 16 resident
// waves (4/SIMD) require.
__global__ __launch_bounds__(1024, 4) void traj_kernel(
    const float* __restrict__ img, const float* __restrict__ obs_pos,
    const int* __restrict__ hist, const float* __restrict__ rel,
    const float* __restrict__ h0, const float* __restrict__ W_ih,
    const float* __restrict__ W_hh, const float* __restrict__ b_ih,
    const float* __restrict__ b_hh, const float* __restrict__ eW,
    const float* __restrict__ eb, const float* __restrict__ pW,
    const float* __restrict__ pb, float* __restrict__ out)
{
  __shared__ unsigned short xh[2][MBLK*200];      // [x(64)|h(128)] bf16, stride 200
  __shared__ unsigned short BoL[6*8*64*8];        // nt=3 B-fragments [kt][w8][lane][8]
  __shared__ float relL[MBLK*40];
  __shared__ float pwL[256];                      // pred_W[:, :128]
  __shared__ float eW0[64], eW1[64], ebL[64];
  __shared__ float imgcL[MBLK*2];

  const int tid  = threadIdx.x;
  const int wv   = tid >> 6;
  const int lane = tid & 63;
  const int q    = lane >> 4;
  const int i    = lane & 15;
  const int w8   = wv & 7;
  const int mtb  = (wv >> 3) << 4;     // 0 or 16
  const int jw   = w8*16 + i;          // hidden unit owned by this lane
  const int g0   = blockIdx.x * MBLK;
  const int dm   = tid >> 5;           // sample 0..31 (32 lanes/sample groups)
  const int i32  = tid & 31;

  // ---- cooperative staging ----
  for (int idx = tid; idx < MBLK*40; idx += 1024) relL[idx] = rel[g0*40 + idx];
  if (tid < 256) pwL[tid] = pW[(tid >> 7)*2176 + (tid & 127)];
  if (tid < 64){ eW0[tid] = eW[tid*2]; eW1[tid] = eW[tid*2+1]; ebL[tid] = eb[tid]; }

  // ---- img_embedding @ pred_W[:,128:].T (once; constant over pred steps) ----
  {
    const float* row = img + (size_t)(g0 + dm)*2048 + i32*64;
    const float* p0  = pW + 128 + i32*64;
    const float* p1  = pW + 2176 + 128 + i32*64;
    float s0 = 0.f, s1 = 0.f;
    #pragma unroll
    for (int v = 0; v < 16; v++){
      float4 a  = ((const float4*)row)[v];
      float4 w0 = ((const float4*)p0)[v];
      float4 w1 = ((const float4*)p1)[v];
      s0 += a.x*w0.x + a.y*w0.y + a.z*w0.z + a.w*w0.w;
      s1 += a.x*w1.x + a.y*w1.y + a.z*w1.z + a.w*w1.w;
    }
    #pragma unroll
    for (int msk = 1; msk < 32; msk <<= 1){
      s0 += __shfl_xor(s0, msk);
      s1 += __shfl_xor(s1, msk);
    }
    if (i32 == 0){ imgcL[dm*2] = s0; imgcL[dm*2+1] = s1; }
  }

  // ---- per-lane persistent state ----
  float h0j = h0[jw];
  float bias_s[4];
  #pragma unroll
  for (int nt = 0; nt < 4; nt++) bias_s[nt] = b_ih[nt*128 + jw] + b_hh[nt*128 + jw];

  unsigned int thrpack = 0;
  float c_s[4], h_s[4];
  #pragma unroll
  for (int r = 0; r < 4; r++){
    int m = mtb + q*4 + r;
    int hv = hist[g0 + m];
    thrpack |= ((unsigned int)(20 - hv) & 255u) << (r*8);  // update iff step >= 20-hist
    c_s[r] = h0j; h_s[r] = h0j;
    xh[0][m*200 + 64 + jw] = f2bf(h0j);
  }

  // ---- weights nt=0..2 -> registers; nt=3 -> LDS fragments ----
  bf16x8 Bf[3][6];
  #pragma unroll
  for (int nt = 0; nt < 3; nt++){
    int row = nt*128 + jw;
    #pragma unroll
    for (int kt = 0; kt < 6; kt++){
      const float* src = (kt < 2) ? (W_ih + row*64  + kt*32     + q*8)
                                  : (W_hh + row*128 + (kt-2)*32 + q*8);
      float4 lo = ((const float4*)src)[0];
      float4 hi = ((const float4*)src)[1];
      bf16x8 tf;
      tf[0]=(short)f2bf(lo.x); tf[1]=(short)f2bf(lo.y); tf[2]=(short)f2bf(lo.z); tf[3]=(short)f2bf(lo.w);
      tf[4]=(short)f2bf(hi.x); tf[5]=(short)f2bf(hi.y); tf[6]=(short)f2bf(hi.z); tf[7]=(short)f2bf(hi.w);
      Bf[nt][kt] = tf;
    }
  }
  if (wv < 8){
    int row = 384 + jw;
    #pragma unroll
    for (int kt = 0; kt < 6; kt++){
      const float* src = (kt < 2) ? (W_ih + row*64  + kt*32     + q*8)
                                  : (W_hh + row*128 + (kt-2)*32 + q*8);
      float4 lo = ((const float4*)src)[0];
      float4 hi = ((const float4*)src)[1];
      bf16x8 tf;
      tf[0]=(short)f2bf(lo.x); tf[1]=(short)f2bf(lo.y); tf[2]=(short)f2bf(lo.z); tf[3]=(short)f2bf(lo.w);
      tf[4]=(short)f2bf(hi.x); tf[5]=(short)f2bf(hi.y); tf[6]=(short)f2bf(hi.z); tf[7]=(short)f2bf(hi.w);
      *((bf16x8*)&BoL[((kt*8 + w8)*64 + lane)*8]) = tf;
    }
  }

  float pos_r = 0.f;
  if (i32 < 2) pos_r = obs_pos[(size_t)(g0 + dm)*40 + 38 + i32];

  __syncthreads();   // staging + BoL + h0 writes visible

  const float ipb0 = imgcL[dm*2]     + pb[0];
  const float ipb1 = imgcL[dm*2 + 1] + pb[1];

  // ---- x_emb(t=1) into xh[0] ----
  {
    int e2 = i32*2;
    float r0 = relL[dm*40 + 2], r1 = relL[dm*40 + 3];
    float a0 = fmaxf(0.f, r0*eW0[e2]   + r1*eW1[e2]   + ebL[e2]);
    float a1 = fmaxf(0.f, r0*eW0[e2+1] + r1*eW1[e2+1] + ebL[e2+1]);
    *((unsigned int*)&xh[0][dm*200 + e2]) =
        (unsigned int)f2bf(a0) | ((unsigned int)f2bf(a1) << 16);
  }

  int b = 0;
  for (int step = 0; step < 49; step++){
    const bool obs = (step < 19);
    __syncthreads();     // xh[b] (x and h) complete

    if (!obs){
      // ---- disp = h @ pwL + imgc + pb; 32 lanes/sample, 4 h-elems each ----
      const unsigned short* hp = &xh[b][dm*200 + 64 + i32*4];
      float s0 = 0.f, s1 = 0.f;
      #pragma unroll
      for (int u = 0; u < 4; u++){
        float hfv = bf2f(hp[u]);
        s0 += hfv * pwL[i32*4 + u];
        s1 += hfv * pwL[128 + i32*4 + u];
      }
      #pragma unroll
      for (int msk = 1; msk < 32; msk <<= 1){
        s0 += __shfl_xor(s0, msk);
        s1 += __shfl_xor(s1, msk);
      }
      float d0 = s0 + ipb0;
      float d1 = s1 + ipb1;
      if (i32 < 2){
        pos_r += (i32 == 0) ? d0 : d1;
        out[(size_t)(g0 + dm)*60 + (size_t)(step - 19)*2 + i32] = pos_r;
      }
      int e2 = i32*2;
      float a0 = fmaxf(0.f, d0*eW0[e2]   + d1*eW1[e2]   + ebL[e2]);
      float a1 = fmaxf(0.f, d0*eW0[e2+1] + d1*eW1[e2+1] + ebL[e2+1]);
      *((unsigned int*)&xh[b][dm*200 + e2]) =
          (unsigned int)f2bf(a0) | ((unsigned int)f2bf(a1) << 16);
      __syncthreads();   // x_emb visible before MFMA reads
    }

    // ---- gates = [x|h] @ W.T + b via MFMA 16x16x32 bf16 ----
    f32x4 acc[4];
    #pragma unroll
    for (int nt = 0; nt < 4; nt++)
      acc[nt] = (f32x4){bias_s[nt], bias_s[nt], bias_s[nt], bias_s[nt]};
    #pragma unroll
    for (int kt = 0; kt < 6; kt++){
      bf16x8 a  = *((const bf16x8*)&xh[b][(mtb + i)*200 + kt*32 + q*8]);
      bf16x8 bo = *((const bf16x8*)&BoL[((kt*8 + w8)*64 + lane)*8]);
      acc[0] = __builtin_amdgcn_mfma_f32_16x16x32_bf16(a, Bf[0][kt], acc[0], 0, 0, 0);
      acc[1] = __builtin_amdgcn_mfma_f32_16x16x32_bf16(a, Bf[1][kt], acc[1], 0, 0, 0);
      acc[2] = __builtin_amdgcn_mfma_f32_16x16x32_bf16(a, Bf[2][kt], acc[2], 0, 0, 0);
      acc[3] = __builtin_amdgcn_mfma_f32_16x16x32_bf16(a, bo,        acc[3], 0, 0, 0);
    }

    // ---- obs: prefetch next step's x_emb (depends only on relL) -> xh[b^1] ----
    if (obs && step < 18){
      int tt = step + 2;
      int e2 = i32*2;
      float r0 = relL[dm*40 + tt*2], r1 = relL[dm*40 + tt*2 + 1];
      float a0 = fmaxf(0.f, r0*eW0[e2]   + r1*eW1[e2]   + ebL[e2]);
      float a1 = fmaxf(0.f, r0*eW0[e2+1] + r1*eW1[e2+1] + ebL[e2+1]);
      *((unsigned int*)&xh[b^1][dm*200 + e2]) =
          (unsigned int)f2bf(a0) | ((unsigned int)f2bf(a1) << 16);
    }

    // ---- nonlinearity + state update; h2 -> xh[b^1] ----
    #pragma unroll
    for (int r = 0; r < 4; r++){
      float ig = acc[0][r];
      float fg = acc[1][r];
      float gg = acc[2][r];
      float og = acc[3][r];
      float c2 = sigm(fg)*c_s[r] + sigm(ig)*tanh_(gg);
      float h2 = sigm(og)*tanh_(c2);
      if (obs){
        bool upd = (int)((thrpack >> (r*8)) & 255u) <= step;
        c2 = upd ? c2 : c_s[r];
        h2 = upd ? h2 : h_s[r];
      }
      c_s[r] = c2; h_s[r] = h2;
      int m = mtb + q*4 + r;
      xh[b^1][m*200 + 64 + jw] = f2bf(h2);
    }

    b ^= 1;
  }
}

extern "C" void kernel_launch(void* const* d_in, const int* in_sizes, int n_in,
                              void* d_out, int out_size, void* d_ws, size_t ws_size,
                              hipStream_t stream){
  const float* img     = (const float*)d_in[0];
  const float* obs_pos = (const float*)d_in[1];
  const int*   hist    = (const int*)d_in[2];
  const float* rel     = (const float*)d_in[3];
  const float* h0      = (const float*)d_in[4];
  const float* W_ih    = (const float*)d_in[5];
  const float* W_hh    = (const float*)d_in[6];
  const float* b_ih    = (const float*)d_in[7];
  const float* b_hh    = (const float*)d_in[8];
  const float* eW      = (const float*)d_in[9];
  const float* eb      = (const float*)d_in[10];
  const float* pW      = (const float*)d_in[11];
  const float* pb      = (const float*)d_in[12];
  float* out = (float*)d_out;
  hipLaunchKernelGGL(traj_kernel, dim3(8192/MBLK), dim3(1024), 0, stream,
                     img, obs_pos, hist, rel, h0, W_ih, W_hh, b_ih, b_hh,
                     eW, eb, pW, pb, out);
}

// Round 4
// 435.466 us; speedup vs baseline: 1.1037x; 1.1037x over previous
//
#include <hip/hip_runtime.h>

#define MBLK 16

typedef __attribute__((ext_vector_type(8))) short bf16x8;
typedef __attribute__((ext_vector_type(4))) float f32x4;

__device__ __forceinline__ unsigned short f2bf(float x){
  unsigned int u = __float_as_uint(x);
  u = u + 0x7FFFu + ((u >> 16) & 1u);
  return (unsigned short)(u >> 16);
}
__device__ __forceinline__ float bf2f(unsigned short s){
  return __uint_as_float(((unsigned int)s) << 16);
}
__device__ __forceinline__ float sigm(float x){
  return __builtin_amdgcn_rcpf(1.0f + __expf(-x));
}
__device__ __forceinline__ float tanh_(float x){
  return 1.0f - 2.0f*__builtin_amdgcn_rcpf(__expf(2.0f*x) + 1.0f);
}

// 512 threads = 8 waves, 16 samples/block, 512 blocks -> 2 blocks/CU
// (4 waves/SIMD). Wave wv owns hidden units jw = wv*16 + (lane&15) for all 4
// gates; one M-tile (16 samples). Gates 0-2 weights register-resident
// (72 VGPR); gate 3 in LDS fragments (49 KB) to stay under the 128-reg cap
// that 2 blocks/CU requires. R3 failed on spills (WRITE_SIZE 159 MB) --
// watch WRITE_SIZE ~2 MB as the no-spill signature.
__global__ __launch_bounds__(512, 4) void traj_kernel(
    const float* __restrict__ img, const float* __restrict__ obs_pos,
    const int* __restrict__ hist, const float* __restrict__ rel,
    const float* __restrict__ h0, const float* __restrict__ W_ih,
    const float* __restrict__ W_hh, const float* __restrict__ b_ih,
    const float* __restrict__ b_hh, const float* __restrict__ eW,
    const float* __restrict__ eb, const float* __restrict__ pW,
    const float* __restrict__ pb, float* __restrict__ out)
{
  __shared__ unsigned short xh[2][MBLK*200];   // [x(64)|h(128)] bf16, stride 200
  __shared__ unsigned short BoL[6*8*64*8];     // gate-3 B-frags [kt][wv][lane][8]
  __shared__ float relL[MBLK*40];
  __shared__ float pwL[256];                   // pred_W[:, :128]
  __shared__ float eW0[64], eW1[64], ebL[64];
  __shared__ float imgcL[MBLK*2];

  const int tid  = threadIdx.x;
  const int wv   = tid >> 6;
  const int lane = tid & 63;
  const int q    = lane >> 4;
  const int i    = lane & 15;
  const int jw   = wv*16 + i;          // hidden unit owned by this lane
  const int g0   = blockIdx.x * MBLK;
  const int dm   = tid >> 5;           // sample 0..15 (32 lanes/sample)
  const int i32  = tid & 31;

  // ---- cooperative staging ----
  for (int idx = tid; idx < MBLK*40; idx += 512) relL[idx] = rel[g0*40 + idx];
  if (tid < 256) pwL[tid] = pW[(tid >> 7)*2176 + (tid & 127)];
  if (tid < 64){ eW0[tid] = eW[tid*2]; eW1[tid] = eW[tid*2+1]; ebL[tid] = eb[tid]; }

  // ---- img_embedding @ pred_W[:,128:].T (once; constant over pred steps) ----
  {
    const float* row = img + (size_t)(g0 + dm)*2048 + i32*64;
    const float* p0  = pW + 128 + i32*64;
    const float* p1  = pW + 2176 + 128 + i32*64;
    float s0 = 0.f, s1 = 0.f;
    #pragma unroll
    for (int v = 0; v < 16; v++){
      float4 a  = ((const float4*)row)[v];
      float4 w0 = ((const float4*)p0)[v];
      float4 w1 = ((const float4*)p1)[v];
      s0 += a.x*w0.x + a.y*w0.y + a.z*w0.z + a.w*w0.w;
      s1 += a.x*w1.x + a.y*w1.y + a.z*w1.z + a.w*w1.w;
    }
    #pragma unroll
    for (int msk = 1; msk < 32; msk <<= 1){
      s0 += __shfl_xor(s0, msk);
      s1 += __shfl_xor(s1, msk);
    }
    if (i32 == 0){ imgcL[dm*2] = s0; imgcL[dm*2+1] = s1; }
  }

  // ---- per-lane persistent state ----
  float h0j = h0[jw];
  float bias_s[4];
  #pragma unroll
  for (int nt = 0; nt < 4; nt++) bias_s[nt] = b_ih[nt*128 + jw] + b_hh[nt*128 + jw];

  unsigned int thrpack = 0;
  float c_s[4], h_s[4];
  #pragma unroll
  for (int r = 0; r < 4; r++){
    int m = q*4 + r;
    int hv = hist[g0 + m];
    thrpack |= ((unsigned int)(20 - hv) & 255u) << (r*8);  // update iff step >= 20-hist
    c_s[r] = h0j; h_s[r] = h0j;
    xh[0][m*200 + 64 + jw] = f2bf(h0j);
  }

  // ---- weights: gates 0-2 -> registers; gate 3 -> LDS fragments ----
  bf16x8 Bf[3][6];
  #pragma unroll
  for (int nt = 0; nt < 3; nt++){
    int row = nt*128 + jw;
    #pragma unroll
    for (int kt = 0; kt < 6; kt++){
      const float* src = (kt < 2) ? (W_ih + row*64  + kt*32     + q*8)
                                  : (W_hh + row*128 + (kt-2)*32 + q*8);
      float4 lo = ((const float4*)src)[0];
      float4 hi = ((const float4*)src)[1];
      bf16x8 tf;
      tf[0]=(short)f2bf(lo.x); tf[1]=(short)f2bf(lo.y); tf[2]=(short)f2bf(lo.z); tf[3]=(short)f2bf(lo.w);
      tf[4]=(short)f2bf(hi.x); tf[5]=(short)f2bf(hi.y); tf[6]=(short)f2bf(hi.z); tf[7]=(short)f2bf(hi.w);
      Bf[nt][kt] = tf;
    }
  }
  {
    int row = 384 + jw;
    #pragma unroll
    for (int kt = 0; kt < 6; kt++){
      const float* src = (kt < 2) ? (W_ih + row*64  + kt*32     + q*8)
                                  : (W_hh + row*128 + (kt-2)*32 + q*8);
      float4 lo = ((const float4*)src)[0];
      float4 hi = ((const float4*)src)[1];
      bf16x8 tf;
      tf[0]=(short)f2bf(lo.x); tf[1]=(short)f2bf(lo.y); tf[2]=(short)f2bf(lo.z); tf[3]=(short)f2bf(lo.w);
      tf[4]=(short)f2bf(hi.x); tf[5]=(short)f2bf(hi.y); tf[6]=(short)f2bf(hi.z); tf[7]=(short)f2bf(hi.w);
      *((bf16x8*)&BoL[((kt*8 + wv)*64 + lane)*8]) = tf;
    }
  }

  float pos_r = 0.f;
  if (i32 < 2) pos_r = obs_pos[(size_t)(g0 + dm)*40 + 38 + i32];

  __syncthreads();   // staging + BoL + h0 writes visible

  const float ipb0 = imgcL[dm*2]     + pb[0];
  const float ipb1 = imgcL[dm*2 + 1] + pb[1];

  // ---- x_emb(t=1) into xh[0] ----
  {
    int e2 = i32*2;
    float r0 = relL[dm*40 + 2], r1 = relL[dm*40 + 3];
    float a0 = fmaxf(0.f, r0*eW0[e2]   + r1*eW1[e2]   + ebL[e2]);
    float a1 = fmaxf(0.f, r0*eW0[e2+1] + r1*eW1[e2+1] + ebL[e2+1]);
    *((unsigned int*)&xh[0][dm*200 + e2]) =
        (unsigned int)f2bf(a0) | ((unsigned int)f2bf(a1) << 16);
  }

  const unsigned short* boP = &BoL[(wv*64 + lane)*8];
  int b = 0;
  for (int step = 0; step < 49; step++){
    const bool obs = (step < 19);
    __syncthreads();     // xh[b] (x and h) complete

    if (!obs){
      // ---- disp = h @ pwL + imgc + pb; 32 lanes/sample, 4 h-elems each ----
      const unsigned short* hp = &xh[b][dm*200 + 64 + i32*4];
      float s0 = 0.f, s1 = 0.f;
      #pragma unroll
      for (int u = 0; u < 4; u++){
        float hfv = bf2f(hp[u]);
        s0 += hfv * pwL[i32*4 + u];
        s1 += hfv * pwL[128 + i32*4 + u];
      }
      #pragma unroll
      for (int msk = 1; msk < 32; msk <<= 1){
        s0 += __shfl_xor(s0, msk);
        s1 += __shfl_xor(s1, msk);
      }
      float d0 = s0 + ipb0;
      float d1 = s1 + ipb1;
      if (i32 < 2){
        pos_r += (i32 == 0) ? d0 : d1;
        out[(size_t)(g0 + dm)*60 + (size_t)(step - 19)*2 + i32] = pos_r;
      }
      int e2 = i32*2;
      float a0 = fmaxf(0.f, d0*eW0[e2]   + d1*eW1[e2]   + ebL[e2]);
      float a1 = fmaxf(0.f, d0*eW0[e2+1] + d1*eW1[e2+1] + ebL[e2+1]);
      *((unsigned int*)&xh[b][dm*200 + e2]) =
          (unsigned int)f2bf(a0) | ((unsigned int)f2bf(a1) << 16);
      __syncthreads();   // x_emb visible before MFMA reads
    }

    // ---- gates = [x|h] @ W.T + b via MFMA 16x16x32 bf16 ----
    f32x4 acc0 = (f32x4){bias_s[0], bias_s[0], bias_s[0], bias_s[0]};
    f32x4 acc1 = (f32x4){bias_s[1], bias_s[1], bias_s[1], bias_s[1]};
    f32x4 acc2 = (f32x4){bias_s[2], bias_s[2], bias_s[2], bias_s[2]};
    f32x4 acc3 = (f32x4){bias_s[3], bias_s[3], bias_s[3], bias_s[3]};
    const unsigned short* aP = &xh[b][i*200 + q*8];
    #pragma unroll
    for (int kt = 0; kt < 6; kt++){
      bf16x8 a  = *((const bf16x8*)(aP  + kt*32));
      bf16x8 bo = *((const bf16x8*)(boP + kt*4096));
      acc0 = __builtin_amdgcn_mfma_f32_16x16x32_bf16(a, Bf[0][kt], acc0, 0, 0, 0);
      acc1 = __builtin_amdgcn_mfma_f32_16x16x32_bf16(a, Bf[1][kt], acc1, 0, 0, 0);
      acc2 = __builtin_amdgcn_mfma_f32_16x16x32_bf16(a, Bf[2][kt], acc2, 0, 0, 0);
      acc3 = __builtin_amdgcn_mfma_f32_16x16x32_bf16(a, bo,        acc3, 0, 0, 0);
    }

    // ---- obs: prefetch next step's x_emb (depends only on relL) -> xh[b^1] ----
    if (obs && step < 18){
      int tt = step + 2;
      int e2 = i32*2;
      float r0 = relL[dm*40 + tt*2], r1 = relL[dm*40 + tt*2 + 1];
      float a0 = fmaxf(0.f, r0*eW0[e2]   + r1*eW1[e2]   + ebL[e2]);
      float a1 = fmaxf(0.f, r0*eW0[e2+1] + r1*eW1[e2+1] + ebL[e2+1]);
      *((unsigned int*)&xh[b^1][dm*200 + e2]) =
          (unsigned int)f2bf(a0) | ((unsigned int)f2bf(a1) << 16);
    }

    // ---- nonlinearity + state update; h2 -> xh[b^1] ----
    #pragma unroll
    for (int r = 0; r < 4; r++){
      float ig = acc0[r];
      float fg = acc1[r];
      float gg = acc2[r];
      float og = acc3[r];
      float c2 = sigm(fg)*c_s[r] + sigm(ig)*tanh_(gg);
      float h2 = sigm(og)*tanh_(c2);
      if (obs){
        bool upd = (int)((thrpack >> (r*8)) & 255u) <= step;
        c2 = upd ? c2 : c_s[r];
        h2 = upd ? h2 : h_s[r];
      }
      c_s[r] = c2; h_s[r] = h2;
      xh[b^1][(q*4 + r)*200 + 64 + jw] = f2bf(h2);
    }

    b ^= 1;
  }
}

extern "C" void kernel_launch(void* const* d_in, const int* in_sizes, int n_in,
                              void* d_out, int out_size, void* d_ws, size_t ws_size,
                              hipStream_t stream){
  const float* img     = (const float*)d_in[0];
  const float* obs_pos = (const float*)d_in[1];
  const int*   hist    = (const int*)d_in[2];
  const float* rel     = (const float*)d_in[3];
  const float* h0      = (const float*)d_in[4];
  const float* W_ih    = (const float*)d_in[5];
  const float* W_hh    = (const float*)d_in[6];
  const float* b_ih    = (const float*)d_in[7];
  const float* b_hh    = (const float*)d_in[8];
  const float* eW      = (const float*)d_in[9];
  const float* eb      = (const float*)d_in[10];
  const float* pW      = (const float*)d_in[11];
  const float* pb      = (const float*)d_in[12];
  float* out = (float*)d_out;
  hipLaunchKernelGGL(traj_kernel, dim3(8192/MBLK), dim3(512), 0, stream,
                     img, obs_pos, hist, rel, h0, W_ih, W_hh, b_ih, b_hh,
                     eW, eb, pW, pb, out);
}

// Round 5
// 294.637 us; speedup vs baseline: 1.6312x; 1.4780x over previous
//
#include <hip/hip_runtime.h>

#define MBLK 32

typedef __attribute__((ext_vector_type(8))) short bf16x8;
typedef __attribute__((ext_vector_type(4))) float f32x4;

__device__ __forceinline__ unsigned short f2bf(float x){
  unsigned int u = __float_as_uint(x);
  u = u + 0x7FFFu + ((u >> 16) & 1u);
  return (unsigned short)(u >> 16);
}
__device__ __forceinline__ float bf2f(unsigned short s){
  return __uint_as_float(((unsigned int)s) << 16);
}
__device__ __forceinline__ float sigm(float x){
  return __builtin_amdgcn_rcpf(1.0f + __expf(-x));
}
__device__ __forceinline__ float tanh_(float x){
  return 1.0f - 2.0f*__builtin_amdgcn_rcpf(__expf(2.0f*x) + 1.0f);
}

// 1024 threads = 16 waves, 32 samples/block, 256 blocks (1 block/CU,
// 4 waves/SIMD). N-split: wave wv owns gate-rows [wv*32, wv*32+32) (2 N-tiles)
// for ALL 32 samples -> weight frags only 48 VGPR/lane (R3/R4 spilled because
// M-split needed 96+). Gates are exchanged through LDS (gl, f32) for the
// nonlinearity, where thread t owns samples t>>5, units (t&31)*4..+3 with c
// persistent in registers. Spill signature to watch: WRITE_SIZE must be ~2 MB.
__global__ __launch_bounds__(1024, 4) void traj_kernel(
    const float* __restrict__ img, const float* __restrict__ obs_pos,
    const int* __restrict__ hist, const float* __restrict__ rel,
    const float* __restrict__ h0, const float* __restrict__ W_ih,
    const float* __restrict__ W_hh, const float* __restrict__ b_ih,
    const float* __restrict__ b_hh, const float* __restrict__ eW,
    const float* __restrict__ eb, const float* __restrict__ pW,
    const float* __restrict__ pb, float* __restrict__ out)
{
  __shared__ unsigned short xh[2][MBLK*200];   // [x(64)|h(128)] bf16, stride 200
  __shared__ float gl[MBLK*516];               // gates f32 [sample][512], pad 4
  __shared__ float relL[MBLK*40];
  __shared__ float pwL[256];                   // pred_W[:, :128]
  __shared__ float eW0[64], eW1[64], ebL[64];
  __shared__ float imgcL[MBLK*2];

  const int tid   = threadIdx.x;
  const int wv    = tid >> 6;
  const int lane  = tid & 63;
  const int q     = lane >> 4;
  const int i     = lane & 15;
  const int nbase = wv*32;           // this wave's gate-row base (N-split)
  const int g0    = blockIdx.x * MBLK;
  const int dm    = tid >> 5;        // sample 0..31 (32 lanes/sample)
  const int i32   = tid & 31;
  const int j4    = i32*4;           // nonlin: 4 hidden units owned

  // ---- cooperative staging ----
  for (int idx = tid; idx < MBLK*40; idx += 1024) relL[idx] = rel[g0*40 + idx];
  if (tid < 256) pwL[tid] = pW[(tid >> 7)*2176 + (tid & 127)];
  if (tid < 64){ eW0[tid] = eW[tid*2]; eW1[tid] = eW[tid*2+1]; ebL[tid] = eb[tid]; }

  // ---- img_embedding @ pred_W[:,128:].T (once; constant over pred steps) ----
  {
    const float* row = img + (size_t)(g0 + dm)*2048 + i32*64;
    const float* p0  = pW + 128 + i32*64;
    const float* p1  = pW + 2176 + 128 + i32*64;
    float s0 = 0.f, s1 = 0.f;
    #pragma unroll
    for (int v = 0; v < 16; v++){
      float4 a  = ((const float4*)row)[v];
      float4 w0 = ((const float4*)p0)[v];
      float4 w1 = ((const float4*)p1)[v];
      s0 += a.x*w0.x + a.y*w0.y + a.z*w0.z + a.w*w0.w;
      s1 += a.x*w1.x + a.y*w1.y + a.z*w1.z + a.w*w1.w;
    }
    #pragma unroll
    for (int msk = 1; msk < 32; msk <<= 1){
      s0 += __shfl_xor(s0, msk);
      s1 += __shfl_xor(s1, msk);
    }
    if (i32 == 0){ imgcL[dm*2] = s0; imgcL[dm*2+1] = s1; }
  }

  // ---- nonlin-role persistent state: sample dm, units j4..j4+3 ----
  float c_s[4], h_s[4];
  {
    unsigned int pk0, pk1;
    float v0 = h0[j4], v1 = h0[j4+1], v2 = h0[j4+2], v3 = h0[j4+3];
    c_s[0]=h_s[0]=v0; c_s[1]=h_s[1]=v1; c_s[2]=h_s[2]=v2; c_s[3]=h_s[3]=v3;
    pk0 = (unsigned int)f2bf(v0) | ((unsigned int)f2bf(v1) << 16);
    pk1 = (unsigned int)f2bf(v2) | ((unsigned int)f2bf(v3) << 16);
    *((uint2*)&xh[0][dm*200 + 64 + j4]) = make_uint2(pk0, pk1);
  }
  const int thr = 20 - hist[g0 + dm];   // update iff step >= thr

  // ---- MFMA-role: bias + weight B-fragments (2 N-tiles, 48 VGPR) ----
  float bias0 = b_ih[nbase + i]      + b_hh[nbase + i];
  float bias1 = b_ih[nbase + 16 + i] + b_hh[nbase + 16 + i];
  bf16x8 Bf[2][6];
  #pragma unroll
  for (int nt = 0; nt < 2; nt++){
    int row = nbase + nt*16 + i;
    #pragma unroll
    for (int kt = 0; kt < 6; kt++){
      const float* src = (kt < 2) ? (W_ih + row*64  + kt*32     + q*8)
                                  : (W_hh + row*128 + (kt-2)*32 + q*8);
      float4 lo = ((const float4*)src)[0];
      float4 hi = ((const float4*)src)[1];
      bf16x8 tf;
      tf[0]=(short)f2bf(lo.x); tf[1]=(short)f2bf(lo.y); tf[2]=(short)f2bf(lo.z); tf[3]=(short)f2bf(lo.w);
      tf[4]=(short)f2bf(hi.x); tf[5]=(short)f2bf(hi.y); tf[6]=(short)f2bf(hi.z); tf[7]=(short)f2bf(hi.w);
      Bf[nt][kt] = tf;
    }
  }

  float pos_r = 0.f;
  if (i32 < 2) pos_r = obs_pos[(size_t)(g0 + dm)*40 + 38 + i32];

  __syncthreads();   // staging + h0 writes visible

  const float ipb0 = imgcL[dm*2]     + pb[0];
  const float ipb1 = imgcL[dm*2 + 1] + pb[1];

  // ---- x_emb(t=1) into xh[0] ----
  {
    int e2 = i32*2;
    float r0 = relL[dm*40 + 2], r1 = relL[dm*40 + 3];
    float a0 = fmaxf(0.f, r0*eW0[e2]   + r1*eW1[e2]   + ebL[e2]);
    float a1 = fmaxf(0.f, r0*eW0[e2+1] + r1*eW1[e2+1] + ebL[e2+1]);
    *((unsigned int*)&xh[0][dm*200 + e2]) =
        (unsigned int)f2bf(a0) | ((unsigned int)f2bf(a1) << 16);
  }

  int b = 0;
  for (int step = 0; step < 49; step++){
    const bool obs = (step < 19);
    __syncthreads();     // xh[b] (x and h) complete; gl free for reuse

    if (!obs){
      // ---- disp = h @ pwL + imgc + pb; 32 lanes/sample, 4 h-elems each ----
      const unsigned short* hp = &xh[b][dm*200 + 64 + i32*4];
      float s0 = 0.f, s1 = 0.f;
      #pragma unroll
      for (int u = 0; u < 4; u++){
        float hfv = bf2f(hp[u]);
        s0 += hfv * pwL[i32*4 + u];
        s1 += hfv * pwL[128 + i32*4 + u];
      }
      #pragma unroll
      for (int msk = 1; msk < 32; msk <<= 1){
        s0 += __shfl_xor(s0, msk);
        s1 += __shfl_xor(s1, msk);
      }
      float d0 = s0 + ipb0;
      float d1 = s1 + ipb1;
      if (i32 < 2){
        pos_r += (i32 == 0) ? d0 : d1;
        out[(size_t)(g0 + dm)*60 + (size_t)(step - 19)*2 + i32] = pos_r;
      }
      int e2 = i32*2;
      float a0 = fmaxf(0.f, d0*eW0[e2]   + d1*eW1[e2]   + ebL[e2]);
      float a1 = fmaxf(0.f, d0*eW0[e2+1] + d1*eW1[e2+1] + ebL[e2+1]);
      *((unsigned int*)&xh[b][dm*200 + e2]) =
          (unsigned int)f2bf(a0) | ((unsigned int)f2bf(a1) << 16);
      __syncthreads();   // x_emb visible before MFMA reads
    }

    // ---- gates = [x|h] @ W.T + b via MFMA; wave computes its 32 gate-rows
    //      for all 32 samples ----
    f32x4 a00 = (f32x4){bias0, bias0, bias0, bias0};
    f32x4 a01 = (f32x4){bias1, bias1, bias1, bias1};
    f32x4 a10 = a00;
    f32x4 a11 = a01;
    const unsigned short* aP = &xh[b][i*200 + q*8];
    #pragma unroll
    for (int kt = 0; kt < 6; kt++){
      bf16x8 av0 = *((const bf16x8*)(aP + kt*32));            // samples 0..15
      bf16x8 av1 = *((const bf16x8*)(aP + 16*200 + kt*32));   // samples 16..31
      a00 = __builtin_amdgcn_mfma_f32_16x16x32_bf16(av0, Bf[0][kt], a00, 0, 0, 0);
      a01 = __builtin_amdgcn_mfma_f32_16x16x32_bf16(av0, Bf[1][kt], a01, 0, 0, 0);
      a10 = __builtin_amdgcn_mfma_f32_16x16x32_bf16(av1, Bf[0][kt], a10, 0, 0, 0);
      a11 = __builtin_amdgcn_mfma_f32_16x16x32_bf16(av1, Bf[1][kt], a11, 0, 0, 0);
    }
    // scatter gates to gl: row m = mt*16 + q*4 + r, col nbase + nt*16 + i
    #pragma unroll
    for (int r = 0; r < 4; r++){
      gl[(q*4 + r)*516      + nbase + i]      = a00[r];
      gl[(q*4 + r)*516      + nbase + 16 + i] = a01[r];
      gl[(16 + q*4 + r)*516 + nbase + i]      = a10[r];
      gl[(16 + q*4 + r)*516 + nbase + 16 + i] = a11[r];
    }

    // ---- obs: prefetch next step's x_emb (depends only on relL) -> xh[b^1] ----
    if (obs && step < 18){
      int tt = step + 2;
      int e2 = i32*2;
      float r0 = relL[dm*40 + tt*2], r1 = relL[dm*40 + tt*2 + 1];
      float a0 = fmaxf(0.f, r0*eW0[e2]   + r1*eW1[e2]   + ebL[e2]);
      float a1 = fmaxf(0.f, r0*eW0[e2+1] + r1*eW1[e2+1] + ebL[e2+1]);
      *((unsigned int*)&xh[b^1][dm*200 + e2]) =
          (unsigned int)f2bf(a0) | ((unsigned int)f2bf(a1) << 16);
    }

    __syncthreads();   // gl complete

    // ---- nonlinearity: thread owns (sample dm, units j4..j4+3) ----
    {
      f32x4 ig = *((const f32x4*)&gl[dm*516 + j4]);
      f32x4 fg = *((const f32x4*)&gl[dm*516 + 128 + j4]);
      f32x4 gg = *((const f32x4*)&gl[dm*516 + 256 + j4]);
      f32x4 og = *((const f32x4*)&gl[dm*516 + 384 + j4]);
      const bool keep = obs && (thr > step);
      unsigned int pk0, pk1;
      unsigned short hb[4];
      #pragma unroll
      for (int r = 0; r < 4; r++){
        float c2 = sigm(fg[r])*c_s[r] + sigm(ig[r])*tanh_(gg[r]);
        float h2 = sigm(og[r])*tanh_(c2);
        c2 = keep ? c_s[r] : c2;
        h2 = keep ? h_s[r] : h2;
        c_s[r] = c2; h_s[r] = h2;
        hb[r] = f2bf(h2);
      }
      pk0 = (unsigned int)hb[0] | ((unsigned int)hb[1] << 16);
      pk1 = (unsigned int)hb[2] | ((unsigned int)hb[3] << 16);
      *((uint2*)&xh[b^1][dm*200 + 64 + j4]) = make_uint2(pk0, pk1);
    }

    b ^= 1;
  }
}

extern "C" void kernel_launch(void* const* d_in, const int* in_sizes, int n_in,
                              void* d_out, int out_size, void* d_ws, size_t ws_size,
                              hipStream_t stream){
  const float* img     = (const float*)d_in[0];
  const float* obs_pos = (const float*)d_in[1];
  const int*   hist    = (const int*)d_in[2];
  const float* rel     = (const float*)d_in[3];
  const float* h0      = (const float*)d_in[4];
  const float* W_ih    = (const float*)d_in[5];
  const float* W_hh    = (const float*)d_in[6];
  const float* b_ih    = (const float*)d_in[7];
  const float* b_hh    = (const float*)d_in[8];
  const float* eW      = (const float*)d_in[9];
  const float* eb      = (const float*)d_in[10];
  const float* pW      = (const float*)d_in[11];
  const float* pb      = (const float*)d_in[12];
  float* out = (float*)d_out;
  hipLaunchKernelGGL(traj_kernel, dim3(8192/MBLK), dim3(1024), 0, stream,
                     img, obs_pos, hist, rel, h0, W_ih, W_hh, b_ih, b_hh,
                     eW, eb, pW, pb, out);
}